// Round 9
// baseline (214.576 us; speedup 1.0000x reference)
//
#include <hip/hip_runtime.h>
#include <math.h>

#define NATOMS 2048
#define DIM 64

typedef float f32x4 __attribute__((ext_vector_type(4)));

// R8 structure (best: 197.0 us), single change: pair loop unroll 2 -> 4.
// ILP-depth probe. __launch_bounds__(256,4) still caps VGPR at 128 so the
// unroll cannot cross the 128-VGPR occupancy cliff (compiler must schedule
// within 128, worst case serializing back to the R8 behavior).
//
// Layout: 8 lanes per pair (group g = lane>>3), 8 pairs per wave-iteration.
// q = lane&7 owns basis dims d0 = q*8..q*8+7 (consecutive -> sin Chebyshev
// recurrence) and output dims {4q..4q+3} U {32+4q..32+4q+3}.
// Each wave owns a contiguous 512-pair chunk (quarter row): i = wid>>2
// (loop-invariant), columns (wid&3)*512 + iter*8 + g. All atoms staged in
// LDS once -> steady-state loop has NO global loads (no vmcnt coupling of
// loads to the output stores).

template <int CTRL>
__device__ __forceinline__ float dpp_add(float v) {
    int m = __builtin_amdgcn_update_dpp(0, __float_as_int(v), CTRL, 0xF, 0xF, true);
    return v + __int_as_float(m);
}
__device__ __forceinline__ float swz_add_xor4(float v) {
    return v + __int_as_float(__builtin_amdgcn_ds_swizzle(__float_as_int(v), 0x101F));
}

__global__ __launch_bounds__(256, 4) void bessel_rbf_kernel(
    const float* __restrict__ atoms,
    const float* __restrict__ w1,   // (64,4)
    const float* __restrict__ w2,   // (4,64)
    float* __restrict__ out)        // (N,N,64)
{
    __shared__ float s_at[NATOMS * 3];   // 24 KB, xyz interleaved

    const int tid  = threadIdx.x;
    const int lane = tid & 63;
    const int waveInBlock = tid >> 6;
    const int q = lane & 7;
    const int g = lane >> 3;
    const int d0 = q * 8;

    // Stage all atoms to LDS: 6144 floats = 1536 float4, 256 threads x 6.
    {
        const float4* ga = reinterpret_cast<const float4*>(atoms);
        float4* sa = reinterpret_cast<float4*>(s_at);
#pragma unroll
        for (int r = 0; r < 6; ++r)
            sa[tid + 256 * r] = ga[tid + 256 * r];
    }

    // w1 rows d0..d0+7
    float w1r[8][4];
#pragma unroll
    for (int k = 0; k < 8; ++k) {
        float4 v = *reinterpret_cast<const float4*>(w1 + (d0 + k) * 4);
        w1r[k][0] = v.x; w1r[k][1] = v.y; w1r[k][2] = v.z; w1r[k][3] = v.w;
    }
    // w2 columns 4q..4q+3 (A) and 32+4q..32+4q+3 (B), pre-scaled by sqrt(2/5)
    const float PREF = 0.6324555320336759f;
    float w2a[4][4], w2b[4][4];
#pragma unroll
    for (int m = 0; m < 4; ++m) {
        float4 va = *reinterpret_cast<const float4*>(w2 + m * DIM + 4 * q);
        float4 vb = *reinterpret_cast<const float4*>(w2 + m * DIM + 32 + 4 * q);
        w2a[m][0] = va.x * PREF; w2a[m][1] = va.y * PREF;
        w2a[m][2] = va.z * PREF; w2a[m][3] = va.w * PREF;
        w2b[m][0] = vb.x * PREF; w2b[m][1] = vb.y * PREF;
        w2b[m][2] = vb.z * PREF; w2b[m][3] = vb.w * PREF;
    }

    __syncthreads();

    // Wave-contiguous chunking: wave wid owns pairs [wid*512, wid*512+512).
    const unsigned wid = __builtin_amdgcn_readfirstlane(
        (unsigned)blockIdx.x * 4u + (unsigned)waveInBlock);
    const int i       = (int)(wid >> 2);          // loop-invariant row
    const int colBase = (int)(wid & 3u) * 512;

    // i-atom (wave-uniform, from LDS broadcast)
    const float ax = s_at[i * 3 + 0];
    const float ay = s_at[i * 3 + 1];
    const float az = s_at[i * 3 + 2];

    const float dk1 = (float)(d0 + 1);
    f32x4* __restrict__ out4 = reinterpret_cast<f32x4*>(out);
    const size_t rowBase = (size_t)i * 2048 + (size_t)colBase;

#pragma unroll 4
    for (int it = 0; it < 64; ++it) {
        const int j = colBase + it * 8 + g;

        const float bx = s_at[j * 3 + 0];
        const float by = s_at[j * 3 + 1];
        const float bz = s_at[j * 3 + 2];

        const float dx = ax - bx, dy = ay - by, dz = az - bz;
        float x = __builtin_amdgcn_sqrtf(fmaf(dx, dx, fmaf(dy, dy, dz * dz)));
        x += 1e-8f;                              // x_ext (sin arg AND divisor)
        const float inv = __builtin_amdgcn_rcpf(x);
        const float xr  = x * 0.1f;              // step angle in revolutions

        // sin((d0+k+1)*2*pi*xr)/x via Chebyshev: s_{k+1} = 2c*s_k - s_{k-1}
        float r0 = dk1 * xr;
        float r1 = r0 + xr;
        r0 = r0 - floorf(r0);
        r1 = r1 - floorf(r1);
        float rc = xr - floorf(xr);
        const float a0   = __builtin_amdgcn_sinf(r0) * inv;
        const float a1   = __builtin_amdgcn_sinf(r1) * inv;
        const float c1   = __builtin_amdgcn_cosf(rc);
        const float twoC = c1 + c1;

        float t[4];
#pragma unroll
        for (int m = 0; m < 4; ++m)
            t[m] = fmaf(a1, w1r[1][m], a0 * w1r[0][m]);
        float sp = a0, sc = a1;
#pragma unroll
        for (int k = 2; k < 8; ++k) {
            const float sn = fmaf(twoC, sc, -sp);
#pragma unroll
            for (int m = 0; m < 4; ++m)
                t[m] = fmaf(sn, w1r[k][m], t[m]);
            sp = sc; sc = sn;
        }

        // Reduce across the 8 lanes of this group.
#pragma unroll
        for (int m = 0; m < 4; ++m) {
            t[m] = dpp_add<0xB1>(t[m]);   // xor1: quad_perm [1,0,3,2]
            t[m] = dpp_add<0x4E>(t[m]);   // xor2: quad_perm [2,3,0,1]
            t[m] = swz_add_xor4(t[m]);    // xor4: ds_swizzle
        }

        // Project to this lane's 8 outputs.
        f32x4 oA, oB;
        oA.x = fmaf(t[0], w2a[0][0], fmaf(t[1], w2a[1][0], fmaf(t[2], w2a[2][0], t[3] * w2a[3][0])));
        oA.y = fmaf(t[0], w2a[0][1], fmaf(t[1], w2a[1][1], fmaf(t[2], w2a[2][1], t[3] * w2a[3][1])));
        oA.z = fmaf(t[0], w2a[0][2], fmaf(t[1], w2a[1][2], fmaf(t[2], w2a[2][2], t[3] * w2a[3][2])));
        oA.w = fmaf(t[0], w2a[0][3], fmaf(t[1], w2a[1][3], fmaf(t[2], w2a[2][3], t[3] * w2a[3][3])));
        oB.x = fmaf(t[0], w2b[0][0], fmaf(t[1], w2b[1][0], fmaf(t[2], w2b[2][0], t[3] * w2b[3][0])));
        oB.y = fmaf(t[0], w2b[0][1], fmaf(t[1], w2b[1][1], fmaf(t[2], w2b[2][1], t[3] * w2b[3][1])));
        oB.z = fmaf(t[0], w2b[0][2], fmaf(t[1], w2b[1][2], fmaf(t[2], w2b[2][2], t[3] * w2b[3][2])));
        oB.w = fmaf(t[0], w2b[0][3], fmaf(t[1], w2b[1][3], fmaf(t[2], w2b[2][3], t[3] * w2b[3][3])));

        const size_t base = (rowBase + (size_t)(it * 8 + g)) * 16;
        out4[base + q]     = oA;
        out4[base + 8 + q] = oB;
    }
}

extern "C" void kernel_launch(void* const* d_in, const int* in_sizes, int n_in,
                              void* d_out, int out_size, void* d_ws, size_t ws_size,
                              hipStream_t stream) {
    const float* atoms = (const float*)d_in[0];
    const float* w1    = (const float*)d_in[1];
    const float* w2    = (const float*)d_in[2];
    float* out         = (float*)d_out;

    // 2048 blocks x 256 threads = 8192 waves; each wave owns 512 contiguous
    // pairs (64 iterations x 8 pairs).
    dim3 grid(2048), block(256);
    hipLaunchKernelGGL(bessel_rbf_kernel, grid, block, 0, stream, atoms, w1, w2, out);
}

// Round 10
// 207.078 us; speedup vs baseline: 1.0362x; 1.0362x over previous
//
#include <hip/hip_runtime.h>
#include <math.h>

#define NATOMS 2048
#define DIM 64

typedef float f32x4 __attribute__((ext_vector_type(4)));

// SYMMETRY EXPLOIT: x(i,j)=x(j,i) exactly in fp, so out[i,j,:]==out[j,i,:].
// Compute upper-triangle pairs only; write each result to BOTH (i,j) and
// (j,i). Halves compute/latency per byte written; write traffic unchanged.
//
// Work decomposition: task t in [0,1024) owns rows iA=t and iB=2047-t,
// j ranges [row&~7, 2047]. itersA = 256-(t>>3), itersB = 1+(t>>3), total
// 257 iterations of 8 pairs — CONSTANT per task. 8 waves interleave each
// task (wave sub = wid&7 takes iterations it ≡ sub mod 8), ~32 iters/wave.
// Near-diagonal rounding duplicates a few pairs; duplicate stores carry
// identical values (race-free, deterministic).
//
// Per-pair kernel identical to R8 (best: 197 us): 8 lanes/pair, q=lane&7
// owns basis dims q*8..q*8+7 (Chebyshev sin recurrence, 1/x folded into
// seeds) and output dims {4q..4q+3} U {32+4q..32+4q+3}; reduce = 2x DPP
// quad_perm add + 1x ds_swizzle xor4; all atoms in LDS (no in-loop global
// loads -> stores never drained by vmcnt waits); unroll 2.

template <int CTRL>
__device__ __forceinline__ float dpp_add(float v) {
    int m = __builtin_amdgcn_update_dpp(0, __float_as_int(v), CTRL, 0xF, 0xF, true);
    return v + __int_as_float(m);
}
__device__ __forceinline__ float swz_add_xor4(float v) {
    return v + __int_as_float(__builtin_amdgcn_ds_swizzle(__float_as_int(v), 0x101F));
}

__global__ __launch_bounds__(256, 4) void bessel_rbf_kernel(
    const float* __restrict__ atoms,
    const float* __restrict__ w1,   // (64,4)
    const float* __restrict__ w2,   // (4,64)
    float* __restrict__ out)        // (N,N,64)
{
    __shared__ float s_at[NATOMS * 3];   // 24 KB, xyz interleaved

    const int tid  = threadIdx.x;
    const int lane = tid & 63;
    const int waveInBlock = tid >> 6;
    const int q = lane & 7;
    const int g = lane >> 3;
    const int d0 = q * 8;

    // Stage all atoms to LDS: 6144 floats = 1536 float4, 256 threads x 6.
    {
        const float4* ga = reinterpret_cast<const float4*>(atoms);
        float4* sa = reinterpret_cast<float4*>(s_at);
#pragma unroll
        for (int r = 0; r < 6; ++r)
            sa[tid + 256 * r] = ga[tid + 256 * r];
    }

    // w1 rows d0..d0+7
    float w1r[8][4];
#pragma unroll
    for (int k = 0; k < 8; ++k) {
        float4 v = *reinterpret_cast<const float4*>(w1 + (d0 + k) * 4);
        w1r[k][0] = v.x; w1r[k][1] = v.y; w1r[k][2] = v.z; w1r[k][3] = v.w;
    }
    // w2 columns 4q..4q+3 (A) and 32+4q..32+4q+3 (B), pre-scaled by sqrt(2/5)
    const float PREF = 0.6324555320336759f;
    float w2a[4][4], w2b[4][4];
#pragma unroll
    for (int m = 0; m < 4; ++m) {
        float4 va = *reinterpret_cast<const float4*>(w2 + m * DIM + 4 * q);
        float4 vb = *reinterpret_cast<const float4*>(w2 + m * DIM + 32 + 4 * q);
        w2a[m][0] = va.x * PREF; w2a[m][1] = va.y * PREF;
        w2a[m][2] = va.z * PREF; w2a[m][3] = va.w * PREF;
        w2b[m][0] = vb.x * PREF; w2b[m][1] = vb.y * PREF;
        w2b[m][2] = vb.z * PREF; w2b[m][3] = vb.w * PREF;
    }

    __syncthreads();

    const unsigned wid = __builtin_amdgcn_readfirstlane(
        (unsigned)blockIdx.x * 4u + (unsigned)waveInBlock);
    const int task = (int)(wid >> 3);          // 0..1023
    const int sub  = (int)(wid & 7u);
    const int iA = task, iB = 2047 - task;
    const int itersA = 256 - (iA >> 3);        // row-A iteration count
    const int jA0 = iA & ~7;
    const int jB0 = iB & ~7;

    // Both rows' atoms (wave-uniform LDS broadcasts, loop-invariant).
    const float axA = s_at[iA*3+0], ayA = s_at[iA*3+1], azA = s_at[iA*3+2];
    const float axB = s_at[iB*3+0], ayB = s_at[iB*3+1], azB = s_at[iB*3+2];

    const float dk1 = (float)(d0 + 1);
    f32x4* __restrict__ out4 = reinterpret_cast<f32x4*>(out);

    auto body = [&](int i, int j0, float ax, float ay, float az) {
        const int j = j0 + g;

        const float bx = s_at[j * 3 + 0];
        const float by = s_at[j * 3 + 1];
        const float bz = s_at[j * 3 + 2];

        const float dx = ax - bx, dy = ay - by, dz = az - bz;
        float x = __builtin_amdgcn_sqrtf(fmaf(dx, dx, fmaf(dy, dy, dz * dz)));
        x += 1e-8f;                              // x_ext (sin arg AND divisor)
        const float inv = __builtin_amdgcn_rcpf(x);
        const float xr  = x * 0.1f;              // step angle in revolutions

        // sin((d0+k+1)*2*pi*xr)/x via Chebyshev: s_{k+1} = 2c*s_k - s_{k-1}
        float r0 = dk1 * xr;
        float r1 = r0 + xr;
        r0 = r0 - floorf(r0);
        r1 = r1 - floorf(r1);
        float rc = xr - floorf(xr);
        const float a0   = __builtin_amdgcn_sinf(r0) * inv;
        const float a1   = __builtin_amdgcn_sinf(r1) * inv;
        const float c1   = __builtin_amdgcn_cosf(rc);
        const float twoC = c1 + c1;

        float t[4];
#pragma unroll
        for (int m = 0; m < 4; ++m)
            t[m] = fmaf(a1, w1r[1][m], a0 * w1r[0][m]);
        float sp = a0, sc = a1;
#pragma unroll
        for (int k = 2; k < 8; ++k) {
            const float sn = fmaf(twoC, sc, -sp);
#pragma unroll
            for (int m = 0; m < 4; ++m)
                t[m] = fmaf(sn, w1r[k][m], t[m]);
            sp = sc; sc = sn;
        }

        // Reduce across the 8 lanes of this group.
#pragma unroll
        for (int m = 0; m < 4; ++m) {
            t[m] = dpp_add<0xB1>(t[m]);   // xor1: quad_perm [1,0,3,2]
            t[m] = dpp_add<0x4E>(t[m]);   // xor2: quad_perm [2,3,0,1]
            t[m] = swz_add_xor4(t[m]);    // xor4: ds_swizzle
        }

        // Project to this lane's 8 outputs.
        f32x4 oA, oB;
        oA.x = fmaf(t[0], w2a[0][0], fmaf(t[1], w2a[1][0], fmaf(t[2], w2a[2][0], t[3] * w2a[3][0])));
        oA.y = fmaf(t[0], w2a[0][1], fmaf(t[1], w2a[1][1], fmaf(t[2], w2a[2][1], t[3] * w2a[3][1])));
        oA.z = fmaf(t[0], w2a[0][2], fmaf(t[1], w2a[1][2], fmaf(t[2], w2a[2][2], t[3] * w2a[3][2])));
        oA.w = fmaf(t[0], w2a[0][3], fmaf(t[1], w2a[1][3], fmaf(t[2], w2a[2][3], t[3] * w2a[3][3])));
        oB.x = fmaf(t[0], w2b[0][0], fmaf(t[1], w2b[1][0], fmaf(t[2], w2b[2][0], t[3] * w2b[3][0])));
        oB.y = fmaf(t[0], w2b[0][1], fmaf(t[1], w2b[1][1], fmaf(t[2], w2b[2][1], t[3] * w2b[3][1])));
        oB.z = fmaf(t[0], w2b[0][2], fmaf(t[1], w2b[1][2], fmaf(t[2], w2b[2][2], t[3] * w2b[3][2])));
        oB.w = fmaf(t[0], w2b[0][3], fmaf(t[1], w2b[1][3], fmaf(t[2], w2b[2][3], t[3] * w2b[3][3])));

        // Direct (i,j) and mirror (j,i). All f32x4 indices < 2^26, fit u32.
        const unsigned bDir = ((unsigned)i * 2048u + (unsigned)j) * 16u;
        const unsigned bMir = ((unsigned)j * 2048u + (unsigned)i) * 16u;
        out4[bDir + q]     = oA;
        out4[bDir + 8 + q] = oB;
        out4[bMir + q]     = oA;
        out4[bMir + 8 + q] = oB;
    };

    int it = sub;
#pragma unroll 2
    for (; it < itersA; it += 8)
        body(iA, jA0 + it * 8, axA, ayA, azA);
#pragma unroll 2
    for (; it < 257; it += 8)
        body(iB, jB0 + (it - itersA) * 8, axB, ayB, azB);
}

extern "C" void kernel_launch(void* const* d_in, const int* in_sizes, int n_in,
                              void* d_out, int out_size, void* d_ws, size_t ws_size,
                              hipStream_t stream) {
    const float* atoms = (const float*)d_in[0];
    const float* w1    = (const float*)d_in[1];
    const float* w2    = (const float*)d_in[2];
    float* out         = (float*)d_out;

    // 2048 blocks x 256 threads = 8192 waves = 1024 tasks x 8 subwaves.
    // Each wave: ~32 iters x 8 pairs x 2 (direct+mirror) = same 128 KB
    // written as before, half the compute chains.
    dim3 grid(2048), block(256);
    hipLaunchKernelGGL(bessel_rbf_kernel, grid, block, 0, stream, atoms, w1, w2, out);
}

// Round 11
// 196.969 us; speedup vs baseline: 1.0894x; 1.0513x over previous
//
#include <hip/hip_runtime.h>
#include <math.h>

#define NATOMS 2048
#define DIM 64

typedef float f32x4 __attribute__((ext_vector_type(4)));

// FINAL (revert to R8, the best measured config: 197.0 us = 5.45 TB/s
// effective write BW, 84% of the fill kernel's demonstrated rate).
//
// Evidence this is the practical roofline:
//  - R10 halved compute per byte (symmetry mirror) -> REGRESSED 10 us:
//    compute exposure is not the limiter; write contiguity is.
//  - ILP probe {1,2,4} = {200.3, 197.0, 214.6} us -> 2 is optimal.
//  - Occupancy probe (64-VGPR / 8 waves/SIMD, R7) -> neutral.
//  - VALU/reduce economy probes (R6/R7) -> neutral.
//  - Removing in-loop global loads (R5) -> -20 us (vmcnt decoupling, real).
//
// Layout: 8 lanes per pair (group g = lane>>3), 8 pairs per wave-iteration.
// q = lane&7 owns basis dims d0 = q*8..q*8+7 (consecutive -> sin Chebyshev
// recurrence) and output dims {4q..4q+3} U {32+4q..32+4q+3}.
// Each wave owns a contiguous 512-pair chunk (quarter row): i = wid>>2
// (loop-invariant), columns (wid&3)*512 + iter*8 + g. All atoms staged in
// LDS once -> steady-state loop has NO global loads (stores never drained
// by vmcnt waits). Reduce = 2x DPP quad_perm add + 1x ds_swizzle xor4.
// 1/x folded into Chebyshev seeds; sqrt(2/5) folded into w2 fragments.

template <int CTRL>
__device__ __forceinline__ float dpp_add(float v) {
    int m = __builtin_amdgcn_update_dpp(0, __float_as_int(v), CTRL, 0xF, 0xF, true);
    return v + __int_as_float(m);
}
__device__ __forceinline__ float swz_add_xor4(float v) {
    return v + __int_as_float(__builtin_amdgcn_ds_swizzle(__float_as_int(v), 0x101F));
}

__global__ __launch_bounds__(256, 4) void bessel_rbf_kernel(
    const float* __restrict__ atoms,
    const float* __restrict__ w1,   // (64,4)
    const float* __restrict__ w2,   // (4,64)
    float* __restrict__ out)        // (N,N,64)
{
    __shared__ float s_at[NATOMS * 3];   // 24 KB, xyz interleaved

    const int tid  = threadIdx.x;
    const int lane = tid & 63;
    const int waveInBlock = tid >> 6;
    const int q = lane & 7;
    const int g = lane >> 3;
    const int d0 = q * 8;

    // Stage all atoms to LDS: 6144 floats = 1536 float4, 256 threads x 6.
    {
        const float4* ga = reinterpret_cast<const float4*>(atoms);
        float4* sa = reinterpret_cast<float4*>(s_at);
#pragma unroll
        for (int r = 0; r < 6; ++r)
            sa[tid + 256 * r] = ga[tid + 256 * r];
    }

    // w1 rows d0..d0+7
    float w1r[8][4];
#pragma unroll
    for (int k = 0; k < 8; ++k) {
        float4 v = *reinterpret_cast<const float4*>(w1 + (d0 + k) * 4);
        w1r[k][0] = v.x; w1r[k][1] = v.y; w1r[k][2] = v.z; w1r[k][3] = v.w;
    }
    // w2 columns 4q..4q+3 (A) and 32+4q..32+4q+3 (B), pre-scaled by sqrt(2/5)
    const float PREF = 0.6324555320336759f;
    float w2a[4][4], w2b[4][4];
#pragma unroll
    for (int m = 0; m < 4; ++m) {
        float4 va = *reinterpret_cast<const float4*>(w2 + m * DIM + 4 * q);
        float4 vb = *reinterpret_cast<const float4*>(w2 + m * DIM + 32 + 4 * q);
        w2a[m][0] = va.x * PREF; w2a[m][1] = va.y * PREF;
        w2a[m][2] = va.z * PREF; w2a[m][3] = va.w * PREF;
        w2b[m][0] = vb.x * PREF; w2b[m][1] = vb.y * PREF;
        w2b[m][2] = vb.z * PREF; w2b[m][3] = vb.w * PREF;
    }

    __syncthreads();

    // Wave-contiguous chunking: wave wid owns pairs [wid*512, wid*512+512).
    const unsigned wid = __builtin_amdgcn_readfirstlane(
        (unsigned)blockIdx.x * 4u + (unsigned)waveInBlock);
    const int i       = (int)(wid >> 2);          // loop-invariant row
    const int colBase = (int)(wid & 3u) * 512;

    // i-atom (wave-uniform, from LDS broadcast)
    const float ax = s_at[i * 3 + 0];
    const float ay = s_at[i * 3 + 1];
    const float az = s_at[i * 3 + 2];

    const float dk1 = (float)(d0 + 1);
    f32x4* __restrict__ out4 = reinterpret_cast<f32x4*>(out);
    const size_t rowBase = (size_t)i * 2048 + (size_t)colBase;

#pragma unroll 2
    for (int it = 0; it < 64; ++it) {
        const int j = colBase + it * 8 + g;

        const float bx = s_at[j * 3 + 0];
        const float by = s_at[j * 3 + 1];
        const float bz = s_at[j * 3 + 2];

        const float dx = ax - bx, dy = ay - by, dz = az - bz;
        float x = __builtin_amdgcn_sqrtf(fmaf(dx, dx, fmaf(dy, dy, dz * dz)));
        x += 1e-8f;                              // x_ext (sin arg AND divisor)
        const float inv = __builtin_amdgcn_rcpf(x);
        const float xr  = x * 0.1f;              // step angle in revolutions

        // sin((d0+k+1)*2*pi*xr)/x via Chebyshev: s_{k+1} = 2c*s_k - s_{k-1}
        float r0 = dk1 * xr;
        float r1 = r0 + xr;
        r0 = r0 - floorf(r0);
        r1 = r1 - floorf(r1);
        float rc = xr - floorf(xr);
        const float a0   = __builtin_amdgcn_sinf(r0) * inv;
        const float a1   = __builtin_amdgcn_sinf(r1) * inv;
        const float c1   = __builtin_amdgcn_cosf(rc);
        const float twoC = c1 + c1;

        float t[4];
#pragma unroll
        for (int m = 0; m < 4; ++m)
            t[m] = fmaf(a1, w1r[1][m], a0 * w1r[0][m]);
        float sp = a0, sc = a1;
#pragma unroll
        for (int k = 2; k < 8; ++k) {
            const float sn = fmaf(twoC, sc, -sp);
#pragma unroll
            for (int m = 0; m < 4; ++m)
                t[m] = fmaf(sn, w1r[k][m], t[m]);
            sp = sc; sc = sn;
        }

        // Reduce across the 8 lanes of this group.
#pragma unroll
        for (int m = 0; m < 4; ++m) {
            t[m] = dpp_add<0xB1>(t[m]);   // xor1: quad_perm [1,0,3,2]
            t[m] = dpp_add<0x4E>(t[m]);   // xor2: quad_perm [2,3,0,1]
            t[m] = swz_add_xor4(t[m]);    // xor4: ds_swizzle
        }

        // Project to this lane's 8 outputs.
        f32x4 oA, oB;
        oA.x = fmaf(t[0], w2a[0][0], fmaf(t[1], w2a[1][0], fmaf(t[2], w2a[2][0], t[3] * w2a[3][0])));
        oA.y = fmaf(t[0], w2a[0][1], fmaf(t[1], w2a[1][1], fmaf(t[2], w2a[2][1], t[3] * w2a[3][1])));
        oA.z = fmaf(t[0], w2a[0][2], fmaf(t[1], w2a[1][2], fmaf(t[2], w2a[2][2], t[3] * w2a[3][2])));
        oA.w = fmaf(t[0], w2a[0][3], fmaf(t[1], w2a[1][3], fmaf(t[2], w2a[2][3], t[3] * w2a[3][3])));
        oB.x = fmaf(t[0], w2b[0][0], fmaf(t[1], w2b[1][0], fmaf(t[2], w2b[2][0], t[3] * w2b[3][0])));
        oB.y = fmaf(t[0], w2b[0][1], fmaf(t[1], w2b[1][1], fmaf(t[2], w2b[2][1], t[3] * w2b[3][1])));
        oB.z = fmaf(t[0], w2b[0][2], fmaf(t[1], w2b[1][2], fmaf(t[2], w2b[2][2], t[3] * w2b[3][2])));
        oB.w = fmaf(t[0], w2b[0][3], fmaf(t[1], w2b[1][3], fmaf(t[2], w2b[2][3], t[3] * w2b[3][3])));

        const size_t base = (rowBase + (size_t)(it * 8 + g)) * 16;
        out4[base + q]     = oA;
        out4[base + 8 + q] = oB;
    }
}

extern "C" void kernel_launch(void* const* d_in, const int* in_sizes, int n_in,
                              void* d_out, int out_size, void* d_ws, size_t ws_size,
                              hipStream_t stream) {
    const float* atoms = (const float*)d_in[0];
    const float* w1    = (const float*)d_in[1];
    const float* w2    = (const float*)d_in[2];
    float* out         = (float*)d_out;

    // 2048 blocks x 256 threads = 8192 waves; each wave owns 512 contiguous
    // pairs (64 iterations x 8 pairs).
    dim3 grid(2048), block(256);
    hipLaunchKernelGGL(bessel_rbf_kernel, grid, block, 0, stream, atoms, w1, w2, out);
}